// Round 1
// baseline (271.520 us; speedup 1.0000x reference)
//
#include <hip/hip_runtime.h>
#include <hip/hip_fp16.h>

#define NB 8
#define NC 1024
#define NIN 256
#define NOUT 256
#define NH 4
#define NNS 5

// float offsets in workspace
#define XP_OFF    0u         // 8*1024*256 = 2097152 floats
#define LOGA_OFF  2097152u   // 1024*1024  = 1048576
#define SRC_OFF   3145728u   // 8192*4     = 32768
#define DST_OFF   3178496u   // 8192*4     = 32768
#define XMEAN_OFF 3211264u   // 8*256      = 2048
#define CS_OFF    3213312u   // 8

// ---------------------------------------------------------------------------
// K1: x @ Wp + bp  (8192x256 @ 256x256), fused x-mean partials and src/dst
// scalar projections. One block = 32 rows x 256 cols.
// ---------------------------------------------------------------------------
__global__ __launch_bounds__(256) void k_proj(
    const float* __restrict__ x, const float* __restrict__ Wp,
    const float* __restrict__ bp, const float* __restrict__ att_w,
    float* __restrict__ xp, float* __restrict__ src_s,
    float* __restrict__ dst_s, float* __restrict__ xmean) {
  __shared__ __align__(16) float xs[32][256];   // 32 KB
  const int t = threadIdx.x;
  const int row0 = blockIdx.x * 32;             // flattened (b*1024 + i)
  const int b = row0 >> 10;

  for (int r = 0; r < 32; ++r) xs[r][t] = x[(row0 + r) * 256 + t];
  __syncthreads();

  // x-mean partial (sum of this block's 32 rows at feature t)
  float ps = 0.f;
  #pragma unroll 8
  for (int r = 0; r < 32; ++r) ps += xs[r][t];
  atomicAdd(&xmean[b * 256 + t], ps);

  float acc[32];
  #pragma unroll
  for (int r = 0; r < 32; ++r) acc[r] = 0.f;

  for (int k = 0; k < 256; k += 4) {
    const float w0 = Wp[(k + 0) * 256 + t];
    const float w1 = Wp[(k + 1) * 256 + t];
    const float w2 = Wp[(k + 2) * 256 + t];
    const float w3 = Wp[(k + 3) * 256 + t];
    #pragma unroll
    for (int r = 0; r < 32; ++r) {
      const float4 xv = *reinterpret_cast<const float4*>(&xs[r][k]);
      acc[r] = fmaf(xv.x, w0, acc[r]);
      acc[r] = fmaf(xv.y, w1, acc[r]);
      acc[r] = fmaf(xv.z, w2, acc[r]);
      acc[r] = fmaf(xv.w, w3, acc[r]);
    }
  }
  const float bias = bp[t];
  #pragma unroll
  for (int r = 0; r < 32; ++r) {
    acc[r] += bias;
    xp[(row0 + r) * 256 + t] = acc[r];
  }

  // src_s[row][h] = sum_d xp[row][h*64+d] * att_w[d]; dst likewise (att_w+64)
  const float wsrc = att_w[t & 63];
  const float wdst = att_w[64 + (t & 63)];
  __syncthreads();
  for (int r = 0; r < 32; ++r) xs[r][t] = acc[r] * wsrc;
  __syncthreads();
  if (t < 128) {
    const int r = t >> 2, h = t & 3;
    float s = 0.f;
    for (int l = 0; l < 64; ++l) s += xs[r][h * 64 + ((l + t) & 63)];
    src_s[(row0 + r) * 4 + h] = s;
  }
  __syncthreads();
  for (int r = 0; r < 32; ++r) xs[r][t] = acc[r] * wdst;
  __syncthreads();
  if (t < 128) {
    const int r = t >> 2, h = t & 3;
    float s = 0.f;
    for (int l = 0; l < 64; ++l) s += xs[r][h * 64 + ((l + t) & 63)];
    dst_s[(row0 + r) * 4 + h] = s;
  }
}

// ---------------------------------------------------------------------------
// K2: logA = log(A_prior + 1e-9), 1M elements (reused 32x by k_attn)
// ---------------------------------------------------------------------------
__global__ __launch_bounds__(256) void k_loga(const float* __restrict__ A,
                                              float* __restrict__ logA) {
  const int i = blockIdx.x * 256 + threadIdx.x;
  logA[i] = logf(A[i] + 1e-9f);
}

// ---------------------------------------------------------------------------
// K3: tiny MLP chain per batch: xmean -> s_logits (output 1) -> softmax -> c
// -> c_s scalar. One block per b.
// ---------------------------------------------------------------------------
__global__ __launch_bounds__(256) void k_head(
    const float* __restrict__ Ws1, const float* __restrict__ bs1,
    const float* __restrict__ Ws2, const float* __restrict__ bs2,
    const float* __restrict__ Wc1, const float* __restrict__ bc1,
    const float* __restrict__ Wc2, const float* __restrict__ bc2,
    const float* __restrict__ att_w, const float* __restrict__ xmean,
    float* __restrict__ cs_ws, float* __restrict__ out_slogits) {
  __shared__ float xm[256];
  __shared__ float h1[128];
  __shared__ float sl[NNS];
  __shared__ float sp[NNS];
  __shared__ float cc1[64];
  __shared__ float cvec[64];
  const int b = blockIdx.x, t = threadIdx.x;
  xm[t] = xmean[b * 256 + t] * (1.f / 1024.f);
  __syncthreads();
  if (t < 128) {
    float a = bs1[t];
    for (int f = 0; f < 256; ++f) a = fmaf(xm[f], Ws1[f * 128 + t], a);
    h1[t] = fmaxf(a, 0.f);
  }
  __syncthreads();
  if (t < NNS) {
    float a = bs2[t];
    for (int k = 0; k < 128; ++k) a = fmaf(h1[k], Ws2[k * NNS + t], a);
    sl[t] = a;
    out_slogits[b * NNS + t] = a;
  }
  __syncthreads();
  if (t == 0) {
    float m = sl[0];
    for (int n = 1; n < NNS; ++n) m = fmaxf(m, sl[n]);
    float s = 0.f;
    for (int n = 0; n < NNS; ++n) { sp[n] = expf(sl[n] - m); s += sp[n]; }
    for (int n = 0; n < NNS; ++n) sp[n] /= s;
  }
  __syncthreads();
  if (t < 64) {
    float a = bc1[t];
    for (int n = 0; n < NNS; ++n) a = fmaf(sp[n], Wc1[n * 64 + t], a);
    cc1[t] = fmaxf(a, 0.f);
  }
  __syncthreads();
  if (t < 64) {
    float a = bc2[t];
    for (int m = 0; m < 64; ++m) a = fmaf(cc1[m], Wc2[m * 64 + t], a);
    cvec[t] = a;
  }
  __syncthreads();
  if (t < 64) {
    float v = cvec[t] * att_w[128 + t];
    #pragma unroll
    for (int m = 32; m; m >>= 1) v += __shfl_xor(v, m);
    if (t == 0) cs_ws[b] = v;
  }
}

// ---------------------------------------------------------------------------
// K4: main attention. Block = (b, 8 consecutive i rows). Wave = head h.
// Phase 1: scores in registers (16/lane), shfl max, exp -> fp16 weights in
// LDS, shfl sum -> 1/denom. Phase 2: j-loop, float4 xp loads, 32 FMA/iter,
// final shfl reduce over the 4 j-subgroups.
// ---------------------------------------------------------------------------
__global__ __launch_bounds__(256) void k_attn(
    const float* __restrict__ xp, const float* __restrict__ logA,
    const float* __restrict__ src_s, const float* __restrict__ dst_s,
    const float* __restrict__ cs_ws, const float* __restrict__ lam,
    float* __restrict__ out) {
  __shared__ __half wl[8][1024][4];   // 64 KB  (exp weights, unnormalized)
  __shared__ __half srcl[1024][4];    // 8 KB
  __shared__ float dinv[8][4];
  const int t = threadIdx.x;
  const int h = t >> 6;               // wave id == head
  const int l = t & 63;
  const int b = blockIdx.x >> 7;      // 128 i-tiles per batch
  const int i0 = (blockIdx.x & 127) << 3;

  // stage src_s for this batch as fp16
  for (int k = 0; k < 16; ++k) {
    const int idx = t + 256 * k;      // = j*4 + h
    srcl[idx >> 2][idx & 3] = __float2half(src_s[(b << 12) + idx]);
  }
  const float csv = cs_ws[b];
  const float lamh = lam[h];
  __syncthreads();

  // ---- phase 1: softmax weights for 8 rows ----
  for (int r = 0; r < 8; ++r) {
    const int i = i0 + r;
    const float dstc = dst_s[((b << 10) + i) * 4 + h] + csv;
    const float* lrow = logA + i * 1024;
    float sc[16];
    float m = -1e30f;
    #pragma unroll
    for (int k = 0; k < 16; ++k) {
      const int j = l + (k << 6);
      float e = __half2float(srcl[j][h]) + dstc;
      e = (e > 0.f) ? e : 0.2f * e;                 // leaky relu 0.2
      const float s = fmaf(lamh, lrow[j], e);
      sc[k] = s;
      m = fmaxf(m, s);
    }
    #pragma unroll
    for (int mm = 32; mm; mm >>= 1) m = fmaxf(m, __shfl_xor(m, mm));
    float sum = 0.f;
    #pragma unroll
    for (int k = 0; k < 16; ++k) {
      const int j = l + (k << 6);
      const float e = __expf(sc[k] - m);
      sum += e;
      wl[r][j][h] = __float2half(e);
    }
    #pragma unroll
    for (int mm = 32; mm; mm >>= 1) sum += __shfl_xor(sum, mm);
    if (l == 0) dinv[r][h] = 1.f / sum;
  }
  __syncthreads();

  // ---- phase 2: out rows = weighted sums of xp ----
  const int q = l & 15;               // d-quad
  const int js = l >> 4;              // j sub-offset
  float4 acc[8];
  #pragma unroll
  for (int r = 0; r < 8; ++r) acc[r] = make_float4(0.f, 0.f, 0.f, 0.f);
  const float* xpb = xp + ((size_t)(b << 10) << 8) + (h << 6) + (q << 2);
  for (int jj = 0; jj < 1024; jj += 4) {
    const int j = jj + js;
    const float4 xv = *reinterpret_cast<const float4*>(xpb + j * 256);
    #pragma unroll
    for (int r = 0; r < 8; ++r) {
      const float wf = __half2float(wl[r][j][h]);
      acc[r].x = fmaf(wf, xv.x, acc[r].x);
      acc[r].y = fmaf(wf, xv.y, acc[r].y);
      acc[r].z = fmaf(wf, xv.z, acc[r].z);
      acc[r].w = fmaf(wf, xv.w, acc[r].w);
    }
  }
  #pragma unroll
  for (int r = 0; r < 8; ++r) {
    #pragma unroll
    for (int mm = 16; mm <= 32; mm <<= 1) {
      acc[r].x += __shfl_xor(acc[r].x, mm);
      acc[r].y += __shfl_xor(acc[r].y, mm);
      acc[r].z += __shfl_xor(acc[r].z, mm);
      acc[r].w += __shfl_xor(acc[r].w, mm);
    }
  }
  if (js == 0) {
    #pragma unroll
    for (int r = 0; r < 8; ++r) {
      const float s = dinv[r][h];
      const float4 o = make_float4(acc[r].x * s, acc[r].y * s,
                                   acc[r].z * s, acc[r].w * s);
      *reinterpret_cast<float4*>(
          out + (((b << 10) + i0 + r) << 8) + (h << 6) + (q << 2)) = o;
    }
  }
}

extern "C" void kernel_launch(void* const* d_in, const int* in_sizes, int n_in,
                              void* d_out, int out_size, void* d_ws,
                              size_t ws_size, hipStream_t stream) {
  const float* x      = (const float*)d_in[0];
  const float* A      = (const float*)d_in[1];
  const float* Wp     = (const float*)d_in[2];
  const float* bp     = (const float*)d_in[3];
  const float* Ws1    = (const float*)d_in[4];
  const float* bs1    = (const float*)d_in[5];
  const float* Ws2    = (const float*)d_in[6];
  const float* bs2    = (const float*)d_in[7];
  const float* Wc1    = (const float*)d_in[8];
  const float* bc1    = (const float*)d_in[9];
  const float* Wc2    = (const float*)d_in[10];
  const float* bc2    = (const float*)d_in[11];
  const float* att_w  = (const float*)d_in[12];
  const float* lam    = (const float*)d_in[13];
  float* out = (float*)d_out;
  float* ws  = (float*)d_ws;

  float* xp    = ws + XP_OFF;
  float* logA  = ws + LOGA_OFF;
  float* src_s = ws + SRC_OFF;
  float* dst_s = ws + DST_OFF;
  float* xmean = ws + XMEAN_OFF;
  float* cs_ws = ws + CS_OFF;

  hipMemsetAsync(xmean, 0, NB * 256 * sizeof(float), stream);

  k_proj<<<dim3(256), dim3(256), 0, stream>>>(x, Wp, bp, att_w, xp, src_s,
                                              dst_s, xmean);
  k_loga<<<dim3(4096), dim3(256), 0, stream>>>(A, logA);
  k_head<<<dim3(NB), dim3(256), 0, stream>>>(Ws1, bs1, Ws2, bs2, Wc1, bc1,
                                             Wc2, bc2, att_w, xmean, cs_ws,
                                             out + NB * NC * NOUT);
  k_attn<<<dim3(1024), dim3(256), 0, stream>>>(xp, logA, src_s, dst_s, cs_ws,
                                               lam, out);
}

// Round 2
// 189.221 us; speedup vs baseline: 1.4349x; 1.4349x over previous
//
#include <hip/hip_runtime.h>
#include <hip/hip_fp16.h>

typedef _Float16 f16x8 __attribute__((ext_vector_type(8)));
typedef float f32x4 __attribute__((ext_vector_type(4)));

#define NB 8
#define NC 1024
#define NNS 5

// float-unit offsets in workspace
// xpT   : 2M halfs  = 1M float slots  [0, 1048576)
// logA  : 1M floats                   [1048576, 2097152)
// srcT  : 32768                       [2097152, ...)
// dstT  : 32768
// xmean : 2048
// cs    : 8
// Wps   : 2048

// ---------------------------------------------------------------------------
// K0: Wps[f][c] = sum_d Wp[f][h*64+d] * att_w[(c<4?0:64)+d],  h=c&3
// ---------------------------------------------------------------------------
__global__ __launch_bounds__(256) void k_pre(const float* __restrict__ Wp,
                                             const float* __restrict__ att_w,
                                             float* __restrict__ Wps) {
  const int c = blockIdx.x;          // 0..7 (0-3 src, 4-7 dst)
  const int h = c & 3;
  const int f = threadIdx.x;
  const float* aw = att_w + ((c >> 2) << 6);
  const float* wrow = Wp + (size_t)f * 256 + (h << 6);
  float s = 0.f;
  #pragma unroll 8
  for (int d = 0; d < 64; ++d) s = fmaf(wrow[d], aw[d], s);
  Wps[(f << 3) + c] = s;
}

// ---------------------------------------------------------------------------
// K1: src_sT[b][h][j], dst_sT[b][h][i] = x @ Wps  (f32, accurate scores)
//     + xmean partials. Block = 32 rows.
// ---------------------------------------------------------------------------
__global__ __launch_bounds__(256) void k_srcdst(
    const float* __restrict__ x, const float* __restrict__ Wps,
    float* __restrict__ srcT, float* __restrict__ dstT,
    float* __restrict__ xmean) {
  __shared__ float xs[32][260];      // padded: breaks 8-way bank conflict
  __shared__ float wp[256][8];
  const int t = threadIdx.x;
  const int row0 = blockIdx.x << 5;
  const int b = row0 >> 10;
  for (int r = 0; r < 32; ++r) xs[r][t] = x[(size_t)(row0 + r) * 256 + t];
  #pragma unroll
  for (int i = 0; i < 8; ++i) ((float*)wp)[t + (i << 8)] = Wps[t + (i << 8)];
  __syncthreads();
  float ps = 0.f;
  #pragma unroll 8
  for (int r = 0; r < 32; ++r) ps += xs[r][t];
  atomicAdd(&xmean[(b << 8) + t], ps);
  const int r = t >> 3, c = t & 7;
  float s = 0.f;
  for (int k = 0; k < 256; ++k) s = fmaf(xs[r][k], wp[k][c], s);
  const int i = (row0 & 1023) + r;
  if (c < 4) srcT[((b << 2) + c) * 1024 + i] = s;
  else       dstT[((b << 2) + (c - 4)) * 1024 + i] = s;
}

// ---------------------------------------------------------------------------
// K2: xpT[b][h][d][i] (fp16) = (x @ Wp + bp) transposed. Block = 16 rows.
// ---------------------------------------------------------------------------
__global__ __launch_bounds__(256) void k_proj(
    const float* __restrict__ x, const float* __restrict__ Wp,
    const float* __restrict__ bp, __half* __restrict__ xpT) {
  __shared__ __align__(16) float xs[16][256];
  const int t = threadIdx.x;
  const int row0 = blockIdx.x << 4;
  const int b = row0 >> 10;
  const int i0 = row0 & 1023;
  #pragma unroll
  for (int r = 0; r < 16; ++r) xs[r][t] = x[(size_t)(row0 + r) * 256 + t];
  __syncthreads();
  float acc[16];
  #pragma unroll
  for (int r = 0; r < 16; ++r) acc[r] = 0.f;
  for (int k = 0; k < 256; k += 4) {
    const float w0 = Wp[(size_t)(k + 0) * 256 + t];
    const float w1 = Wp[(size_t)(k + 1) * 256 + t];
    const float w2 = Wp[(size_t)(k + 2) * 256 + t];
    const float w3 = Wp[(size_t)(k + 3) * 256 + t];
    #pragma unroll
    for (int r = 0; r < 16; ++r) {
      const float4 xv = *reinterpret_cast<const float4*>(&xs[r][k]);
      acc[r] = fmaf(xv.x, w0, acc[r]);
      acc[r] = fmaf(xv.y, w1, acc[r]);
      acc[r] = fmaf(xv.z, w2, acc[r]);
      acc[r] = fmaf(xv.w, w3, acc[r]);
    }
  }
  const float bias = bp[t];
  f16x8 o0, o1;
  #pragma unroll
  for (int r = 0; r < 8; ++r) {
    o0[r] = (_Float16)(acc[r] + bias);
    o1[r] = (_Float16)(acc[r + 8] + bias);
  }
  // thread t = feature (h*64+d): 16 consecutive i values -> contiguous 32B
  __half* dst = xpT + ((size_t)(b << 8) + t) * 1024 + i0;
  *reinterpret_cast<f16x8*>(dst) = o0;
  *reinterpret_cast<f16x8*>(dst + 8) = o1;
}

// ---------------------------------------------------------------------------
// K3: logA = log(A_prior + 1e-9)
// ---------------------------------------------------------------------------
__global__ __launch_bounds__(256) void k_loga(const float* __restrict__ A,
                                              float* __restrict__ logA) {
  const int i = blockIdx.x * 256 + threadIdx.x;
  logA[i] = logf(A[i] + 1e-9f);
}

// ---------------------------------------------------------------------------
// K4: tiny per-batch MLP head -> s_logits (output 1), c_s scalar
// ---------------------------------------------------------------------------
__global__ __launch_bounds__(256) void k_head(
    const float* __restrict__ Ws1, const float* __restrict__ bs1,
    const float* __restrict__ Ws2, const float* __restrict__ bs2,
    const float* __restrict__ Wc1, const float* __restrict__ bc1,
    const float* __restrict__ Wc2, const float* __restrict__ bc2,
    const float* __restrict__ att_w, const float* __restrict__ xmean,
    float* __restrict__ cs_ws, float* __restrict__ out_slogits) {
  __shared__ float xm[256];
  __shared__ float h1[128];
  __shared__ float sl[NNS];
  __shared__ float sp[NNS];
  __shared__ float cc1[64];
  __shared__ float cvec[64];
  const int b = blockIdx.x, t = threadIdx.x;
  xm[t] = xmean[b * 256 + t] * (1.f / 1024.f);
  __syncthreads();
  if (t < 128) {
    float a = bs1[t];
    for (int f = 0; f < 256; ++f) a = fmaf(xm[f], Ws1[f * 128 + t], a);
    h1[t] = fmaxf(a, 0.f);
  }
  __syncthreads();
  if (t < NNS) {
    float a = bs2[t];
    for (int k = 0; k < 128; ++k) a = fmaf(h1[k], Ws2[k * NNS + t], a);
    sl[t] = a;
    out_slogits[b * NNS + t] = a;
  }
  __syncthreads();
  if (t == 0) {
    float m = sl[0];
    for (int n = 1; n < NNS; ++n) m = fmaxf(m, sl[n]);
    float s = 0.f;
    for (int n = 0; n < NNS; ++n) { sp[n] = expf(sl[n] - m); s += sp[n]; }
    for (int n = 0; n < NNS; ++n) sp[n] /= s;
  }
  __syncthreads();
  if (t < 64) {
    float a = bc1[t];
    for (int n = 0; n < NNS; ++n) a = fmaf(sp[n], Wc1[n * 64 + t], a);
    cc1[t] = fmaxf(a, 0.f);
  }
  __syncthreads();
  if (t < 64) {
    float a = bc2[t];
    for (int m = 0; m < 64; ++m) a = fmaf(cc1[m], Wc2[m * 64 + t], a);
    cvec[t] = a;
  }
  __syncthreads();
  if (t < 64) {
    float v = cvec[t] * att_w[128 + t];
    #pragma unroll
    for (int m = 32; m; m >>= 1) v += __shfl_xor(v, m);
    if (t == 0) cs_ws[b] = v;
  }
}

// ---------------------------------------------------------------------------
// K5: attention. Block = (b, 16 i-rows), 512 threads = 8 waves.
// Wave w: h = w&3, rh = w>>2 (row-half for phase1, d-half for phase2).
// Phase 1: f32 scores, wave softmax, fp16 exp-weights -> swizzled LDS.
// Phase 2: MFMA 16x16x32_f16: alpha[16x1024] @ xpT_h[1024x64].
// ---------------------------------------------------------------------------
__global__ __launch_bounds__(512) void k_attn(
    const __half* __restrict__ xpT, const float* __restrict__ logA,
    const float* __restrict__ srcT, const float* __restrict__ dstT,
    const float* __restrict__ cs_ws, const float* __restrict__ lam,
    float* __restrict__ out) {
  __shared__ __align__(16) __half wl[4][16][1024];   // 128 KB
  __shared__ float dinv[4][16];
  const int t = threadIdx.x;
  const int l = t & 63;
  const int w = t >> 6;
  const int h = w & 3;
  const int rh = w >> 2;
  const int b = blockIdx.x >> 6;
  const int i0 = (blockIdx.x & 63) << 4;
  const float csv = cs_ws[b];
  const float lamh = lam[h];
  const float* srcb = srcT + ((b << 2) + h) * 1024;
  const float* dstb = dstT + ((b << 2) + h) * 1024;
  char* wbase = (char*)&wl[h][0][0];

  // ---- phase 1: rows rh*8 .. rh*8+7 of this tile, all 1024 j ----
  for (int r = 0; r < 8; ++r) {
    const int row = (rh << 3) + r;
    const int i = i0 + row;
    const float dstc = dstb[i] + csv;
    const float* lrow = logA + (size_t)i * 1024;
    float sc[16];
    float m = -1e30f;
    #pragma unroll
    for (int k = 0; k < 16; ++k) {
      const int j = l + (k << 6);
      float e = srcb[j] + dstc;
      e = (e > 0.f) ? e : 0.2f * e;            // leaky relu 0.2
      const float s = fmaf(lamh, lrow[j], e);
      sc[k] = s;
      m = fmaxf(m, s);
    }
    #pragma unroll
    for (int mm = 32; mm; mm >>= 1) m = fmaxf(m, __shfl_xor(m, mm));
    float sum = 0.f;
    const int xr = (row & 7) << 4;             // XOR swizzle (16B units)
    #pragma unroll
    for (int k = 0; k < 16; ++k) {
      const int j = l + (k << 6);
      const float e = __expf(sc[k] - m);
      sum += e;
      *(__half*)(wbase + (((row << 11) | (j << 1)) ^ xr)) = __float2half(e);
    }
    #pragma unroll
    for (int mm = 32; mm; mm >>= 1) sum += __shfl_xor(sum, mm);
    if (l == 0) dinv[h][row] = 1.f / sum;
  }
  __syncthreads();

  // ---- phase 2: MFMA over K=1024; this wave does N-half rh (32 cols) ----
  const int lm = l & 15;                        // A row / B col / D col
  const int q = l >> 4;                         // k-group
  const int xa = (lm & 7) << 4;
  const int abase = lm << 11;
  f32x4 acc0 = {0.f, 0.f, 0.f, 0.f};
  f32x4 acc1 = {0.f, 0.f, 0.f, 0.f};
  const __half* xb0 =
      xpT + (((size_t)((b << 2) + h)) << 16) + (size_t)((rh << 5) + lm) * 1024;
  const __half* xb1 = xb0 + 16 * 1024;
  #pragma unroll 4
  for (int kk = 0; kk < 32; ++kk) {
    const int j0 = (kk << 5) + (q << 3);
    const f16x8 af =
        *(const f16x8*)(wbase + (abase | ((j0 << 1) ^ xa)));
    const f16x8 bf0 = *(const f16x8*)(xb0 + j0);
    const f16x8 bf1 = *(const f16x8*)(xb1 + j0);
    acc0 = __builtin_amdgcn_mfma_f32_16x16x32_f16(af, bf0, acc0, 0, 0, 0);
    acc1 = __builtin_amdgcn_mfma_f32_16x16x32_f16(af, bf1, acc1, 0, 0, 0);
  }
  // C/D layout: col = lane&15, row = (lane>>4)*4 + reg
  float* ob = out + (((size_t)(b << 10) + i0) << 8) + (h << 6) + (rh << 5) + lm;
  #pragma unroll
  for (int reg = 0; reg < 4; ++reg) {
    const int mrow = (q << 2) + reg;
    const float dv = dinv[h][mrow];
    ob[(size_t)mrow << 8] = acc0[reg] * dv;
    ob[((size_t)mrow << 8) + 16] = acc1[reg] * dv;
  }
}

extern "C" void kernel_launch(void* const* d_in, const int* in_sizes, int n_in,
                              void* d_out, int out_size, void* d_ws,
                              size_t ws_size, hipStream_t stream) {
  const float* x     = (const float*)d_in[0];
  const float* A     = (const float*)d_in[1];
  const float* Wp    = (const float*)d_in[2];
  const float* bp    = (const float*)d_in[3];
  const float* Ws1   = (const float*)d_in[4];
  const float* bs1   = (const float*)d_in[5];
  const float* Ws2   = (const float*)d_in[6];
  const float* bs2   = (const float*)d_in[7];
  const float* Wc1   = (const float*)d_in[8];
  const float* bc1   = (const float*)d_in[9];
  const float* Wc2   = (const float*)d_in[10];
  const float* bc2   = (const float*)d_in[11];
  const float* att_w = (const float*)d_in[12];
  const float* lam   = (const float*)d_in[13];
  float* out = (float*)d_out;
  float* ws  = (float*)d_ws;

  __half* xpT  = (__half*)ws;            // 2M halfs (4 MB)
  float* logA  = ws + 1048576;
  float* srcT  = ws + 2097152;
  float* dstT  = srcT + 32768;
  float* xmean = dstT + 32768;
  float* cs    = xmean + 2048;
  float* Wps   = cs + 8;

  hipMemsetAsync(xmean, 0, 2048 * sizeof(float), stream);

  k_pre<<<dim3(8), dim3(256), 0, stream>>>(Wp, att_w, Wps);
  k_srcdst<<<dim3(256), dim3(256), 0, stream>>>(x, Wps, srcT, dstT, xmean);
  k_proj<<<dim3(512), dim3(256), 0, stream>>>(x, Wp, bp, xpT);
  k_loga<<<dim3(4096), dim3(256), 0, stream>>>(A, logA);
  k_head<<<dim3(NB), dim3(256), 0, stream>>>(Ws1, bs1, Ws2, bs2, Wc1, bc1,
                                             Wc2, bc2, att_w, xmean, cs,
                                             out + NB * NC * 256);
  k_attn<<<dim3(512), dim3(512), 0, stream>>>(xpT, logA, srcT, dstT, cs, lam,
                                              out);
}

// Round 3
// 169.759 us; speedup vs baseline: 1.5994x; 1.1146x over previous
//
#include <hip/hip_runtime.h>
#include <hip/hip_fp16.h>

typedef _Float16 f16x8 __attribute__((ext_vector_type(8)));
typedef _Float16 f16x4 __attribute__((ext_vector_type(4)));
typedef float f32x4 __attribute__((ext_vector_type(4)));

#define NB 8
#define NNS 5

// workspace float offsets
// xpT  : 2M halfs = 1M floats   [0, 1048576)
// xh   : 2M halfs = 1M floats   [1048576, 2097152)   (aliased by logA)
// logA : 1M floats              [1048576, 2097152)   (written AFTER k_projM reads xh)
// srcP : 32768                  [2097152, 2129920)
// dstT : 32768                  [2129920, 2162688)
// xmean: 2048                   [2162688, 2164736)
// cs   : 8                      [2164736, 2164744)
// WpsT : 2048                   [2164744, 2166792)
// WpTh : 64K halfs = 32768 fl   [2166792, 2199560)

// ---------------------------------------------------------------------------
// K0: WpsT[c][f] = sum_d Wp[f][h*64+d] * att_w[(c<4?0:64)+d],  h=c&3
// ---------------------------------------------------------------------------
__global__ __launch_bounds__(256) void k_pre(const float* __restrict__ Wp,
                                             const float* __restrict__ att_w,
                                             float* __restrict__ WpsT) {
  const int c = blockIdx.x;          // 0..7 (0-3 src, 4-7 dst)
  const int h = c & 3;
  const int f = threadIdx.x;
  const float* aw = att_w + ((c >> 2) << 6);
  const float* wrow = Wp + (size_t)f * 256 + (h << 6);
  float s = 0.f;
  #pragma unroll 8
  for (int d = 0; d < 64; ++d) s = fmaf(wrow[d], aw[d], s);
  WpsT[(c << 8) + f] = s;
}

// ---------------------------------------------------------------------------
// K1: WpTh[f][k] = fp16(Wp[k][f])  (transposed fp16 B-operand for k_projM)
// ---------------------------------------------------------------------------
__global__ __launch_bounds__(256) void k_wt(const float* __restrict__ Wp,
                                            __half* __restrict__ WpTh) {
  const int f = blockIdx.x;
  const int k = threadIdx.x;
  WpTh[(f << 8) + k] = __float2half(Wp[(size_t)k * 256 + f]);
}

// ---------------------------------------------------------------------------
// K2: srcP[b][j][h], dstT[b][h][i] = x @ Wps; xmean partials; xh = fp16(x).
//     Block = 32 rows, 256 threads: thread = (row r=t>>3, col c=t&7).
// ---------------------------------------------------------------------------
__global__ __launch_bounds__(256) void k_srcdst(
    const float* __restrict__ x, const float* __restrict__ WpsT,
    float* __restrict__ srcP, float* __restrict__ dstT,
    float* __restrict__ xmean, __half* __restrict__ xh) {
  __shared__ __align__(16) float xs[32][260];
  const int t = threadIdx.x;
  const int row0 = blockIdx.x << 5;
  const int b = row0 >> 10;
  for (int r = 0; r < 32; ++r) {
    const float v = x[(size_t)(row0 + r) * 256 + t];
    xs[r][t] = v;
    xh[(size_t)(row0 + r) * 256 + t] = __float2half(v);
  }
  __syncthreads();
  float ps = 0.f;
  #pragma unroll 8
  for (int r = 0; r < 32; ++r) ps += xs[r][t];
  atomicAdd(&xmean[(b << 8) + t], ps);

  const int r = t >> 3, c = t & 7;
  const float* wrow = WpsT + (c << 8);
  f32x4 a0 = {0.f, 0.f, 0.f, 0.f}, a1 = {0.f, 0.f, 0.f, 0.f};
  for (int k = 0; k < 256; k += 8) {
    const f32x4 xa = *(const f32x4*)&xs[r][k];
    const f32x4 xb = *(const f32x4*)&xs[r][k + 4];
    const f32x4 wa = *(const f32x4*)(wrow + k);
    const f32x4 wb = *(const f32x4*)(wrow + k + 4);
    #pragma unroll
    for (int u = 0; u < 4; ++u) {
      a0[u] = fmaf(xa[u], wa[u], a0[u]);
      a1[u] = fmaf(xb[u], wb[u], a1[u]);
    }
  }
  const float s = (a0[0] + a0[1]) + (a0[2] + a0[3]) +
                  (a1[0] + a1[1]) + (a1[2] + a1[3]);
  const int i = (row0 & 1023) + r;
  if (c < 4) srcP[(((b << 10) + i) << 2) + c] = s;
  else       dstT[(((b << 2) + (c - 4)) << 10) + i] = s;
}

// ---------------------------------------------------------------------------
// K3: xpT[b*256+f][i] = fp16(x @ Wp + bp), via MFMA 16x16x32 f16.
// Grid 512: bm = blk>>2 (64-row group), nh = blk&3 (64-col quarter).
// Wave w: m-tile rows R0 = bm*64 + w*16. A-frags from xh, B from WpTh.
// ---------------------------------------------------------------------------
__global__ __launch_bounds__(256) void k_projM(
    const __half* __restrict__ xh, const __half* __restrict__ WpTh,
    const float* __restrict__ bp, __half* __restrict__ xpT) {
  const int t = threadIdx.x;
  const int l = t & 63, w = t >> 6;
  const int lm = l & 15, q = l >> 4;
  const int bm = blockIdx.x >> 2, nh = blockIdx.x & 3;
  const int R0 = (bm << 6) + (w << 4);
  const int f0 = nh << 6;

  const __half* arow = xh + (size_t)(R0 + lm) * 256 + (q << 3);
  f16x8 ah[8];
  #pragma unroll
  for (int kk = 0; kk < 8; ++kk)
    ah[kk] = *(const f16x8*)(arow + (kk << 5));

  f32x4 acc[4];
  #pragma unroll
  for (int n = 0; n < 4; ++n) acc[n] = (f32x4){0.f, 0.f, 0.f, 0.f};
  #pragma unroll
  for (int n = 0; n < 4; ++n) {
    const __half* brow = WpTh + (size_t)(f0 + (n << 4) + lm) * 256 + (q << 3);
    #pragma unroll
    for (int kk = 0; kk < 8; ++kk) {
      const f16x8 bf = *(const f16x8*)(brow + (kk << 5));
      acc[n] = __builtin_amdgcn_mfma_f32_16x16x32_f16(ah[kk], bf, acc[n],
                                                      0, 0, 0);
    }
  }
  const int b = R0 >> 10;
  const int il = (R0 & 1023) + (q << 2);
  #pragma unroll
  for (int n = 0; n < 4; ++n) {
    const int f = f0 + (n << 4) + lm;
    const float bias = bp[f];
    f16x4 o;
    #pragma unroll
    for (int reg = 0; reg < 4; ++reg) o[reg] = (_Float16)(acc[n][reg] + bias);
    *(f16x4*)(xpT + (((size_t)((b << 8) + f)) << 10) + il) = o;
  }
}

// ---------------------------------------------------------------------------
// K4: logA = log(A_prior + 1e-9)   (runs after k_projM; aliases xh)
// ---------------------------------------------------------------------------
__global__ __launch_bounds__(256) void k_loga(const float* __restrict__ A,
                                              float* __restrict__ logA) {
  const int i = blockIdx.x * 256 + threadIdx.x;
  logA[i] = logf(A[i] + 1e-9f);
}

// ---------------------------------------------------------------------------
// K5: tiny per-batch MLP head -> s_logits (output 1), c_s scalar
// ---------------------------------------------------------------------------
__global__ __launch_bounds__(256) void k_head(
    const float* __restrict__ Ws1, const float* __restrict__ bs1,
    const float* __restrict__ Ws2, const float* __restrict__ bs2,
    const float* __restrict__ Wc1, const float* __restrict__ bc1,
    const float* __restrict__ Wc2, const float* __restrict__ bc2,
    const float* __restrict__ att_w, const float* __restrict__ xmean,
    float* __restrict__ cs_ws, float* __restrict__ out_slogits) {
  __shared__ float xm[256];
  __shared__ float h1[128];
  __shared__ float sl[NNS];
  __shared__ float sp[NNS];
  __shared__ float cc1[64];
  __shared__ float cvec[64];
  const int b = blockIdx.x, t = threadIdx.x;
  xm[t] = xmean[b * 256 + t] * (1.f / 1024.f);
  __syncthreads();
  if (t < 128) {
    float a = bs1[t];
    for (int f = 0; f < 256; ++f) a = fmaf(xm[f], Ws1[f * 128 + t], a);
    h1[t] = fmaxf(a, 0.f);
  }
  __syncthreads();
  if (t < NNS) {
    float a = bs2[t];
    for (int k = 0; k < 128; ++k) a = fmaf(h1[k], Ws2[k * NNS + t], a);
    sl[t] = a;
    out_slogits[b * NNS + t] = a;
  }
  __syncthreads();
  if (t == 0) {
    float m = sl[0];
    for (int n = 1; n < NNS; ++n) m = fmaxf(m, sl[n]);
    float s = 0.f;
    for (int n = 0; n < NNS; ++n) { sp[n] = expf(sl[n] - m); s += sp[n]; }
    for (int n = 0; n < NNS; ++n) sp[n] /= s;
  }
  __syncthreads();
  if (t < 64) {
    float a = bc1[t];
    for (int n = 0; n < NNS; ++n) a = fmaf(sp[n], Wc1[n * 64 + t], a);
    cc1[t] = fmaxf(a, 0.f);
  }
  __syncthreads();
  if (t < 64) {
    float a = bc2[t];
    for (int m = 0; m < 64; ++m) a = fmaf(cc1[m], Wc2[m * 64 + t], a);
    cvec[t] = a;
  }
  __syncthreads();
  if (t < 64) {
    float v = cvec[t] * att_w[128 + t];
    #pragma unroll
    for (int m = 32; m; m >>= 1) v += __shfl_xor(v, m);
    if (t == 0) cs_ws[b] = v;
  }
}

// ---------------------------------------------------------------------------
// K6: attention, flash-chunked (CJ=512, 2 chunks), no max pass.
// Block = (b, 16 i-rows), 512 threads = 8 waves, 2 blocks/CU.
// Phase1: wave w -> rows {2w, 2w+1} x ALL 4 heads (logA loaded once/cell).
// Phase2: wave w -> (h=w&3, d-half rh=w>>2), MFMA 16x16x32 f16.
// ---------------------------------------------------------------------------
__global__ __launch_bounds__(512, 4) void k_attn(
    const __half* __restrict__ xpT, const float* __restrict__ logA,
    const float* __restrict__ srcP, const float* __restrict__ dstT,
    const float* __restrict__ cs_ws, const float* __restrict__ lam,
    float* __restrict__ out) {
  __shared__ __align__(16) __half wl[4][16][512];   // 64 KB, XOR-swizzled
  __shared__ float dinv[4][16];
  const int t = threadIdx.x;
  const int l = t & 63;
  const int w = t >> 6;
  const int b = blockIdx.x >> 6;
  const int i0 = (blockIdx.x & 63) << 4;
  const float csv = cs_ws[b];
  float lamv[4], dstc[2][4];
  #pragma unroll
  for (int h = 0; h < 4; ++h) {
    lamv[h] = lam[h];
    #pragma unroll
    for (int rr = 0; rr < 2; ++rr)
      dstc[rr][h] = dstT[(((b << 2) + h) << 10) + i0 + 2 * w + rr] + csv;
  }
  const int r0g = i0 + 2 * w;
  char* wlb = (char*)wl;

  // phase2 ids
  const int h2 = w & 3, rh = w >> 2;
  const int lm = l & 15, q = l >> 4;
  f32x4 acc0 = {0.f, 0.f, 0.f, 0.f};
  f32x4 acc1 = {0.f, 0.f, 0.f, 0.f};
  const __half* xb0 =
      xpT + (((size_t)((b << 8) + (h2 << 6) + (rh << 5) + lm)) << 10);
  const __half* xb1 = xb0 + (16 << 10);

  float sums[2][4];
  #pragma unroll
  for (int rr = 0; rr < 2; ++rr)
    #pragma unroll
    for (int h = 0; h < 4; ++h) sums[rr][h] = 0.f;

  for (int cc = 0; cc < 2; ++cc) {
    // ---- phase 1: scores+exp for j in [cc*512, cc*512+512) ----
    for (int st = 0; st < 8; ++st) {
      const int jl = (st << 6) + l;
      const int jg = (cc << 9) + jl;
      const float la0 = logA[(size_t)r0g * 1024 + jg];
      const float la1 = logA[(size_t)(r0g + 1) * 1024 + jg];
      const f32x4 sv = *(const f32x4*)(srcP + (((b << 10) + jg) << 2));
      #pragma unroll
      for (int h = 0; h < 4; ++h) {
        #pragma unroll
        for (int rr = 0; rr < 2; ++rr) {
          const float e = sv[h] + dstc[rr][h];
          const float lk = fmaxf(e, 0.2f * e);
          const float s = fmaf(lamv[h], rr ? la1 : la0, lk);
          const float p = __expf(s);
          sums[rr][h] += p;
          const int row = 2 * w + rr;
          *(__half*)(wlb + (h << 14) + (row << 10) +
                     ((jl << 1) ^ ((row & 7) << 4))) = __float2half(p);
        }
      }
    }
    if (cc == 1) {
      // final denominators
      #pragma unroll
      for (int rr = 0; rr < 2; ++rr)
        #pragma unroll
        for (int h = 0; h < 4; ++h) {
          float s = sums[rr][h];
          #pragma unroll
          for (int mm = 32; mm; mm >>= 1) s += __shfl_xor(s, mm);
          sums[rr][h] = s;
        }
      if (l == 0) {
        #pragma unroll
        for (int rr = 0; rr < 2; ++rr)
          #pragma unroll
          for (int h = 0; h < 4; ++h)
            dinv[h][2 * w + rr] = 1.f / sums[rr][h];
      }
    }
    __syncthreads();
    // ---- phase 2: MFMA over this chunk's K=512 ----
    const char* ab = wlb + (h2 << 14) + (lm << 10);
    const int xa = (lm & 7) << 4;
    #pragma unroll 4
    for (int kk = 0; kk < 16; ++kk) {
      const int jl = (kk << 5) + (q << 3);
      const f16x8 af = *(const f16x8*)(ab + ((jl << 1) ^ xa));
      const f16x8 bf0 = *(const f16x8*)(xb0 + (cc << 9) + jl);
      const f16x8 bf1 = *(const f16x8*)(xb1 + (cc << 9) + jl);
      acc0 = __builtin_amdgcn_mfma_f32_16x16x32_f16(af, bf0, acc0, 0, 0, 0);
      acc1 = __builtin_amdgcn_mfma_f32_16x16x32_f16(af, bf1, acc1, 0, 0, 0);
    }
    __syncthreads();
  }
  // epilogue: C/D layout col = lane&15, row = (lane>>4)*4 + reg
  float* ob =
      out + (((size_t)((b << 10) + i0)) << 8) + (h2 << 6) + (rh << 5) + lm;
  #pragma unroll
  for (int reg = 0; reg < 4; ++reg) {
    const int mrow = (q << 2) + reg;
    const float dv = dinv[h2][mrow];
    ob[(size_t)mrow << 8] = acc0[reg] * dv;
    ob[((size_t)mrow << 8) + 16] = acc1[reg] * dv;
  }
}

extern "C" void kernel_launch(void* const* d_in, const int* in_sizes, int n_in,
                              void* d_out, int out_size, void* d_ws,
                              size_t ws_size, hipStream_t stream) {
  const float* x     = (const float*)d_in[0];
  const float* A     = (const float*)d_in[1];
  const float* Wp    = (const float*)d_in[2];
  const float* bp    = (const float*)d_in[3];
  const float* Ws1   = (const float*)d_in[4];
  const float* bs1   = (const float*)d_in[5];
  const float* Ws2   = (const float*)d_in[6];
  const float* bs2   = (const float*)d_in[7];
  const float* Wc1   = (const float*)d_in[8];
  const float* bc1   = (const float*)d_in[9];
  const float* Wc2   = (const float*)d_in[10];
  const float* bc2   = (const float*)d_in[11];
  const float* att_w = (const float*)d_in[12];
  const float* lam   = (const float*)d_in[13];
  float* out = (float*)d_out;
  float* ws  = (float*)d_ws;

  __half* xpT  = (__half*)ws;                 // 2M halfs
  __half* xh   = (__half*)(ws + 1048576);     // 2M halfs (aliased by logA)
  float* logA  = ws + 1048576;                // written after k_projM
  float* srcP  = ws + 2097152;
  float* dstT  = ws + 2129920;
  float* xmean = ws + 2162688;
  float* cs    = ws + 2164736;
  float* WpsT  = ws + 2164744;
  __half* WpTh = (__half*)(ws + 2166792);

  hipMemsetAsync(xmean, 0, 2048 * sizeof(float), stream);

  k_pre<<<dim3(8), dim3(256), 0, stream>>>(Wp, att_w, WpsT);
  k_wt<<<dim3(256), dim3(256), 0, stream>>>(Wp, WpTh);
  k_srcdst<<<dim3(256), dim3(256), 0, stream>>>(x, WpsT, srcP, dstT, xmean,
                                                xh);
  k_projM<<<dim3(512), dim3(256), 0, stream>>>(xh, WpTh, bp, xpT);
  k_loga<<<dim3(4096), dim3(256), 0, stream>>>(A, logA);
  k_head<<<dim3(NB), dim3(256), 0, stream>>>(Ws1, bs1, Ws2, bs2, Wc1, bc1,
                                             Wc2, bc2, att_w, xmean, cs,
                                             out + NB * 1024 * 256);
  k_attn<<<dim3(512), dim3(512), 0, stream>>>(xpT, logA, srcP, dstT, cs, lam,
                                              out);
}

// Round 4
// 159.493 us; speedup vs baseline: 1.7024x; 1.0644x over previous
//
#include <hip/hip_runtime.h>
#include <hip/hip_fp16.h>

typedef _Float16 f16x8 __attribute__((ext_vector_type(8)));
typedef _Float16 f16x4 __attribute__((ext_vector_type(4)));
typedef float f32x4 __attribute__((ext_vector_type(4)));

#define NB 8
#define NNS 5

// workspace float offsets
// xpT  : 2M halfs = 1M float slots  [0, 1048576)
// srcP : 32768  [1048576, 1081344)   layout [b][j][h] f32
// dstT : 32768  [1081344, 1114112)   layout [b][h][i] f32
// xmean: 2048   [1114112, 1116160)
// cs   : 8      [1116160, 1116168)
// WpTh : 64K halfs = 32768 floats [1116168, 1148936)

// ---------------------------------------------------------------------------
// K0: WpTh[f][k] = fp16(Wp[k][f])  (transposed fp16 B-operand for k_projM)
// grid 256 = k-row; thread = f (coalesced read).
// ---------------------------------------------------------------------------
__global__ __launch_bounds__(256) void k_prew(const float* __restrict__ Wp,
                                              __half* __restrict__ WpTh) {
  const int k = blockIdx.x;
  const int f = threadIdx.x;
  WpTh[(f << 8) + k] = __float2half(Wp[(k << 8) + f]);
}

// ---------------------------------------------------------------------------
// K1: xmean partials (atomic). Block = 32 rows.
// ---------------------------------------------------------------------------
__global__ __launch_bounds__(256) void k_mean(const float* __restrict__ x,
                                              float* __restrict__ xmean) {
  const int t = threadIdx.x;
  const int row0 = blockIdx.x << 5;
  const int b = row0 >> 10;
  float ps = 0.f;
  #pragma unroll 8
  for (int r = 0; r < 32; ++r) ps += x[(size_t)(row0 + r) * 256 + t];
  atomicAdd(&xmean[(b << 8) + t], ps);
}

// ---------------------------------------------------------------------------
// K2: xpT[b*256+f][i] = fp16(x @ Wp + bp) via MFMA 16x16x32 f16, PLUS fused
// src/dst head-scores from the accumulators (head h == col-quarter nh).
// Grid 512: bm = blk>>2 (64-row group), nh = blk&3. Wave w: rows bm*64+w*16.
// ---------------------------------------------------------------------------
__global__ __launch_bounds__(256, 4) void k_projM(
    const float* __restrict__ x, const __half* __restrict__ WpTh,
    const float* __restrict__ bp, const float* __restrict__ att_w,
    __half* __restrict__ xpT, float* __restrict__ srcP,
    float* __restrict__ dstT) {
  const int t = threadIdx.x;
  const int l = t & 63, w = t >> 6;
  const int lm = l & 15, q = l >> 4;
  const int bm = blockIdx.x >> 2, nh = blockIdx.x & 3;
  const int R0 = (bm << 6) + (w << 4);
  const int f0 = nh << 6;

  // A-fragments: row R0+lm, k = kk*32 + q*8 + [0..7], f32 -> f16 in-reg
  const float* arow = x + (size_t)(R0 + lm) * 256 + (q << 3);
  f16x8 ah[8];
  #pragma unroll
  for (int kk = 0; kk < 8; ++kk) {
    const f32x4 xa = *(const f32x4*)(arow + (kk << 5));
    const f32x4 xb = *(const f32x4*)(arow + (kk << 5) + 4);
    f16x8 v;
    #pragma unroll
    for (int u = 0; u < 4; ++u) {
      v[u] = (_Float16)xa[u];
      v[u + 4] = (_Float16)xb[u];
    }
    ah[kk] = v;
  }

  f32x4 acc[4];
  #pragma unroll
  for (int n = 0; n < 4; ++n) acc[n] = (f32x4){0.f, 0.f, 0.f, 0.f};
  #pragma unroll
  for (int n = 0; n < 4; ++n) {
    const __half* brow = WpTh + (size_t)(f0 + (n << 4) + lm) * 256 + (q << 3);
    #pragma unroll
    for (int kk = 0; kk < 8; ++kk) {
      const f16x8 bf = *(const f16x8*)(brow + (kk << 5));
      acc[n] = __builtin_amdgcn_mfma_f32_16x16x32_f16(ah[kk], bf, acc[n],
                                                      0, 0, 0);
    }
  }

  // epilogue: C/D layout col = lane&15, row = (lane>>4)*4 + reg
  const int b = R0 >> 10;
  const int il = (R0 & 1023) + (q << 2);
  float wsn[4], wdn[4];
  #pragma unroll
  for (int n = 0; n < 4; ++n) {
    const int d = (n << 4) + lm;      // d within head (f0 = nh*64)
    wsn[n] = att_w[d];
    wdn[n] = att_w[64 + d];
  }
  #pragma unroll
  for (int n = 0; n < 4; ++n) {
    const int f = f0 + (n << 4) + lm;
    const float bias = bp[f];
    f16x4 o;
    #pragma unroll
    for (int reg = 0; reg < 4; ++reg) {
      acc[n][reg] += bias;
      o[reg] = (_Float16)acc[n][reg];
    }
    *(f16x4*)(xpT + (((size_t)((b << 8) + f)) << 10) + il) = o;
  }
  #pragma unroll
  for (int reg = 0; reg < 4; ++reg) {
    float ss = 0.f, ds = 0.f;
    #pragma unroll
    for (int n = 0; n < 4; ++n) {
      ss = fmaf(acc[n][reg], wsn[n], ss);
      ds = fmaf(acc[n][reg], wdn[n], ds);
    }
    #pragma unroll
    for (int off = 1; off < 16; off <<= 1) {
      ss += __shfl_xor(ss, off);
      ds += __shfl_xor(ds, off);
    }
    if (lm == 0) {
      const int i = il + reg;
      srcP[((((b << 10) + i)) << 2) + nh] = ss;
      dstT[(((b << 2) + nh) << 10) + i] = ds;
    }
  }
}

// ---------------------------------------------------------------------------
// K3: tiny per-batch MLP head -> s_logits (output 1), c_s scalar
// ---------------------------------------------------------------------------
__global__ __launch_bounds__(256) void k_head(
    const float* __restrict__ Ws1, const float* __restrict__ bs1,
    const float* __restrict__ Ws2, const float* __restrict__ bs2,
    const float* __restrict__ Wc1, const float* __restrict__ bc1,
    const float* __restrict__ Wc2, const float* __restrict__ bc2,
    const float* __restrict__ att_w, const float* __restrict__ xmean,
    float* __restrict__ cs_ws, float* __restrict__ out_slogits) {
  __shared__ float xm[256];
  __shared__ float h1[128];
  __shared__ float sl[NNS];
  __shared__ float sp[NNS];
  __shared__ float cc1[64];
  __shared__ float cvec[64];
  const int b = blockIdx.x, t = threadIdx.x;
  xm[t] = xmean[b * 256 + t] * (1.f / 1024.f);
  __syncthreads();
  if (t < 128) {
    float a = bs1[t];
    for (int f = 0; f < 256; ++f) a = fmaf(xm[f], Ws1[f * 128 + t], a);
    h1[t] = fmaxf(a, 0.f);
  }
  __syncthreads();
  if (t < NNS) {
    float a = bs2[t];
    for (int k = 0; k < 128; ++k) a = fmaf(h1[k], Ws2[k * NNS + t], a);
    sl[t] = a;
    out_slogits[b * NNS + t] = a;
  }
  __syncthreads();
  if (t == 0) {
    float m = sl[0];
    for (int n = 1; n < NNS; ++n) m = fmaxf(m, sl[n]);
    float s = 0.f;
    for (int n = 0; n < NNS; ++n) { sp[n] = expf(sl[n] - m); s += sp[n]; }
    for (int n = 0; n < NNS; ++n) sp[n] /= s;
  }
  __syncthreads();
  if (t < 64) {
    float a = bc1[t];
    for (int n = 0; n < NNS; ++n) a = fmaf(sp[n], Wc1[n * 64 + t], a);
    cc1[t] = fmaxf(a, 0.f);
  }
  __syncthreads();
  if (t < 64) {
    float a = bc2[t];
    for (int m = 0; m < 64; ++m) a = fmaf(cc1[m], Wc2[m * 64 + t], a);
    cvec[t] = a;
  }
  __syncthreads();
  if (t < 64) {
    float v = cvec[t] * att_w[128 + t];
    #pragma unroll
    for (int m = 32; m; m >>= 1) v += __shfl_xor(v, m);
    if (t == 0) cs_ws[b] = v;
  }
}

// ---------------------------------------------------------------------------
// K4: attention, 4 chunks of 256 j, inline log2(A+eps), no max pass.
// Block = (b, 16 i-rows), 512 threads = 8 waves. wl = 32 KB.
// Phase1: wave w -> rows {2w,2w+1} x 4 heads, float2 A loads, half2 stores.
// Phase2: wave w -> (h=w&3, d-half rh=w>>2), MFMA 16x16x32 f16.
// ---------------------------------------------------------------------------
__global__ __launch_bounds__(512, 4) void k_attn(
    const __half* __restrict__ xpT, const float* __restrict__ A,
    const float* __restrict__ srcP, const float* __restrict__ dstT,
    const float* __restrict__ cs_ws, const float* __restrict__ lam,
    float* __restrict__ out) {
  __shared__ __align__(16) __half wl[4][16][256];   // 32 KB, XOR-swizzled
  __shared__ float dinv[4][16];
  const int t = threadIdx.x;
  const int l = t & 63;
  const int w = t >> 6;
  const int b = blockIdx.x >> 6;
  const int i0 = (blockIdx.x & 63) << 4;
  const float csv = cs_ws[b];
  float lam2[4], dstc[2][4];
  #pragma unroll
  for (int h = 0; h < 4; ++h) {
    lam2[h] = lam[h] * 0.69314718056f;     // fold ln2: lam*ln(A) = lam2*log2(A)
    #pragma unroll
    for (int rr = 0; rr < 2; ++rr)
      dstc[rr][h] = dstT[(((b << 2) + h) << 10) + i0 + 2 * w + rr] + csv;
  }
  const int r0g = i0 + 2 * w;
  const float* Ar0 = A + (size_t)r0g * 1024;
  const float* Ar1 = Ar0 + 1024;
  char* wlb = (char*)wl;

  // phase2 ids
  const int h2 = w & 3, rh = w >> 2;
  const int lm = l & 15, q = l >> 4;
  f32x4 acc0 = {0.f, 0.f, 0.f, 0.f};
  f32x4 acc1 = {0.f, 0.f, 0.f, 0.f};
  const __half* xb0 =
      xpT + (((size_t)((b << 8) + (h2 << 6) + (rh << 5) + lm)) << 10);
  const __half* xb1 = xb0 + (16 << 10);

  float sums[2][4];
  #pragma unroll
  for (int rr = 0; rr < 2; ++rr)
    #pragma unroll
    for (int h = 0; h < 4; ++h) sums[rr][h] = 0.f;

  for (int cc = 0; cc < 4; ++cc) {
    // ---- phase 1: j in [cc*256, cc*256+256), 2 j per lane per step ----
    #pragma unroll
    for (int st = 0; st < 2; ++st) {
      const int jl = (st << 7) + (l << 1);
      const int jg = (cc << 8) + jl;
      const float2 a0 = *(const float2*)(Ar0 + jg);
      const float2 a1 = *(const float2*)(Ar1 + jg);
      const f32x4 sv0 = *(const f32x4*)(srcP + (((b << 10) + jg) << 2));
      const f32x4 sv1 = *(const f32x4*)(srcP + (((b << 10) + jg + 1) << 2));
      float la[2][2];
      la[0][0] = __log2f(a0.x + 1e-9f);
      la[0][1] = __log2f(a0.y + 1e-9f);
      la[1][0] = __log2f(a1.x + 1e-9f);
      la[1][1] = __log2f(a1.y + 1e-9f);
      #pragma unroll
      for (int h = 0; h < 4; ++h) {
        #pragma unroll
        for (int rr = 0; rr < 2; ++rr) {
          __half2 pk;
          #pragma unroll
          for (int jj = 0; jj < 2; ++jj) {
            const float e = (jj ? sv1[h] : sv0[h]) + dstc[rr][h];
            const float lk = fmaxf(e, 0.2f * e);   // leaky relu 0.2
            const float s = fmaf(lam2[h], la[rr][jj], lk);
            const float p = __expf(s);
            sums[rr][h] += p;
            if (jj) pk.y = __float2half(p); else pk.x = __float2half(p);
          }
          const int row = 2 * w + rr;
          *(__half2*)(wlb + (h << 13) + (row << 9) +
                      ((jl << 1) ^ ((row & 7) << 4))) = pk;
        }
      }
    }
    if (cc == 3) {
      #pragma unroll
      for (int rr = 0; rr < 2; ++rr)
        #pragma unroll
        for (int h = 0; h < 4; ++h) {
          float s = sums[rr][h];
          #pragma unroll
          for (int mm = 32; mm; mm >>= 1) s += __shfl_xor(s, mm);
          sums[rr][h] = s;
        }
      if (l == 0) {
        #pragma unroll
        for (int rr = 0; rr < 2; ++rr)
          #pragma unroll
          for (int h = 0; h < 4; ++h)
            dinv[h][2 * w + rr] = 1.f / sums[rr][h];
      }
    }
    __syncthreads();
    // ---- phase 2: MFMA over this chunk's K=256 ----
    const char* ab = wlb + (h2 << 13) + (lm << 9);
    const int xa = (lm & 7) << 4;
    const __half* xb0c = xb0 + (cc << 8);
    const __half* xb1c = xb1 + (cc << 8);
    #pragma unroll
    for (int kk = 0; kk < 8; ++kk) {
      const int jl2 = (kk << 5) + (q << 3);
      const f16x8 af = *(const f16x8*)(ab + ((jl2 << 1) ^ xa));
      const f16x8 bf0 = *(const f16x8*)(xb0c + jl2);
      const f16x8 bf1 = *(const f16x8*)(xb1c + jl2);
      acc0 = __builtin_amdgcn_mfma_f32_16x16x32_f16(af, bf0, acc0, 0, 0, 0);
      acc1 = __builtin_amdgcn_mfma_f32_16x16x32_f16(af, bf1, acc1, 0, 0, 0);
    }
    __syncthreads();
  }
  // epilogue: C/D layout col = lane&15, row = (lane>>4)*4 + reg
  float* ob =
      out + (((size_t)((b << 10) + i0)) << 8) + (h2 << 6) + (rh << 5) + lm;
  #pragma unroll
  for (int reg = 0; reg < 4; ++reg) {
    const int mrow = (q << 2) + reg;
    const float dv = dinv[h2][mrow];
    ob[(size_t)mrow << 8] = acc0[reg] * dv;
    ob[((size_t)mrow << 8) + 16] = acc1[reg] * dv;
  }
}

extern "C" void kernel_launch(void* const* d_in, const int* in_sizes, int n_in,
                              void* d_out, int out_size, void* d_ws,
                              size_t ws_size, hipStream_t stream) {
  const float* x     = (const float*)d_in[0];
  const float* A     = (const float*)d_in[1];
  const float* Wp    = (const float*)d_in[2];
  const float* bp    = (const float*)d_in[3];
  const float* Ws1   = (const float*)d_in[4];
  const float* bs1   = (const float*)d_in[5];
  const float* Ws2   = (const float*)d_in[6];
  const float* bs2   = (const float*)d_in[7];
  const float* Wc1   = (const float*)d_in[8];
  const float* bc1   = (const float*)d_in[9];
  const float* Wc2   = (const float*)d_in[10];
  const float* bc2   = (const float*)d_in[11];
  const float* att_w = (const float*)d_in[12];
  const float* lam   = (const float*)d_in[13];
  float* out = (float*)d_out;
  float* ws  = (float*)d_ws;

  __half* xpT  = (__half*)ws;             // 2M halfs
  float* srcP  = ws + 1048576;
  float* dstT  = ws + 1081344;
  float* xmean = ws + 1114112;
  float* cs    = ws + 1116160;
  __half* WpTh = (__half*)(ws + 1116168);

  hipMemsetAsync(xmean, 0, 2048 * sizeof(float), stream);

  k_prew<<<dim3(256), dim3(256), 0, stream>>>(Wp, WpTh);
  k_mean<<<dim3(256), dim3(256), 0, stream>>>(x, xmean);
  k_projM<<<dim3(512), dim3(256), 0, stream>>>(x, WpTh, bp, att_w, xpT, srcP,
                                               dstT);
  k_head<<<dim3(NB), dim3(256), 0, stream>>>(Ws1, bs1, Ws2, bs2, Wc1, bc1,
                                             Wc2, bc2, att_w, xmean, cs,
                                             out + NB * 1024 * 256);
  k_attn<<<dim3(512), dim3(512), 0, stream>>>(xpT, A, srcP, dstT, cs, lam,
                                              out);
}